// Round 6
// baseline (983.976 us; speedup 1.0000x reference)
//
#include <hip/hip_runtime.h>
#include <cstddef>

#define NCF 10

struct TFKeys { unsigned k[2 * NCF]; };

typedef __attribute__((ext_vector_type(8))) _Float16 f16x8;
typedef __attribute__((ext_vector_type(4))) float f32x4;

// Threefry-2x32, 20 rounds (JAX-compatible, partitionable semantics verified R1).
__host__ __device__ __forceinline__ void tf2x32(unsigned k0, unsigned k1,
                                                unsigned x0, unsigned x1,
                                                unsigned& o0, unsigned& o1) {
  const unsigned ks2 = k0 ^ k1 ^ 0x1BD11BDAu;
  x0 += k0; x1 += k1;
#define TF_R(r) x0 += x1; x1 = (x1 << (r)) | (x1 >> (32 - (r))); x1 ^= x0;
  TF_R(13) TF_R(15) TF_R(26) TF_R(6)
  x0 += k1;  x1 += ks2 + 1u;
  TF_R(17) TF_R(29) TF_R(16) TF_R(24)
  x0 += ks2; x1 += k0 + 2u;
  TF_R(13) TF_R(15) TF_R(26) TF_R(6)
  x0 += k0;  x1 += k1 + 3u;
  TF_R(17) TF_R(29) TF_R(16) TF_R(24)
  x0 += k1;  x1 += ks2 + 4u;
  TF_R(13) TF_R(15) TF_R(26) TF_R(6)
  x0 += ks2; x1 += k0 + 5u;
#undef TF_R
  o0 = x0; o1 = x1;
}

__device__ __forceinline__ float u01(unsigned bits) {
  return __uint_as_float((bits >> 9) | 0x3f800000u) - 1.0f;
}

// fp16x3 split of 8 floats: x = hi + lo, |x - hi - lo| <= 2^-24 |x|.
__device__ __forceinline__ void split44(const float4 a, const float4 b,
                                        f16x8& hh, f16x8& ll) {
  const float v[8] = {a.x, a.y, a.z, a.w, b.x, b.y, b.z, b.w};
#pragma unroll
  for (int e = 0; e < 8; ++e) {
    const _Float16 h = (_Float16)v[e];
    hh[e] = h;
    ll[e] = (_Float16)(v[e] - (float)h);
  }
}

// D += Ah*Bh + Ah*Bl + Al*Bh  (drops Al*Bl ~ 2^-24)
#define MFMA3(acc, ah, al, bh, bl)                                          \
  acc = __builtin_amdgcn_mfma_f32_16x16x32_f16(ah, bh, acc, 0, 0, 0);       \
  acc = __builtin_amdgcn_mfma_f32_16x16x32_f16(ah, bl, acc, 0, 0, 0);       \
  acc = __builtin_amdgcn_mfma_f32_16x16x32_f16(al, bh, acc, 0, 0, 0);

// Stage W[K][N] (row-major f32) into hi/lo B-fragment layout (verified R2):
// frag elem ((kt*NTN+nt)*64+lane)*8+e  <->  W[kt*32+(lane>>4)*8+e][nt*16+(lane&15)]
template <int K, int N, int NT>
__device__ __forceinline__ void stage_frags(const float* __restrict__ W,
                                            _Float16* fh, _Float16* fl, int t) {
  constexpr int NTN = N / 16;
  for (int i = t; i < K * N; i += NT) {
    const int e = i & 7, lane = (i >> 3) & 63, tile = i >> 9;
    const int kt = tile / NTN, nt = tile % NTN;
    const int k = kt * 32 + ((lane >> 4) << 3) + e;
    const int c = nt * 16 + (lane & 15);
    const float w = W[k * N + c];
    const _Float16 h = (_Float16)w;
    fh[i] = h;
    fl[i] = (_Float16)(w - (float)h);
  }
}

// ---------------------------------------------------------------------------
// Prep kernel: pre-stage all pass-weight fragments to global (d_ws, 80KB).
// f16 layout: [0)w1a_hi [8192)w1a_lo [16384)w2_hi [24576)w2_lo [32768)w3_hi
// [36864)w3_lo. Main kernel copies w1a_hi/w2 to LDS; reads w1a_lo/w3 direct
// from global (L1/L2-resident, 24KB hot set) to fit LDS in 64KB -> 2 blocks/CU.
// ---------------------------------------------------------------------------
__global__ __launch_bounds__(512)
void prep_frags(const float* __restrict__ W1, const float* __restrict__ W2,
                const float* __restrict__ W3, _Float16* __restrict__ g) {
  const int t = threadIdx.x;
  stage_frags<64, 128, 512>(W1 + 256 * 128, g, g + 8192, t);
  stage_frags<128, 64, 512>(W2, g + 16384, g + 24576, t);
  stage_frags<64, 64, 512>(W3, g + 32768, g + 36864, t);
}

// [16][32] chunk buffer with XOR swizzle: naive layout is a 16-way bank
// conflict on the b128 reads (16 lanes stride 128B); swizzled -> 2-way (free).
__device__ __forceinline__ int swz(int row, int col) {
  return (row << 5) + (col ^ ((row & 7) << 2));
}

// ---------------------------------------------------------------------------
// Fused kernel: 512 threads = 8 independent waves (16 samples each), LDS 64KB
// -> 2 blocks/CU = 16 waves/CU = 4 waves/EU. launch_bounds(512,2) is the R3
// config that produced clean 88-VGPR codegen (2nd arg behaves as CUDA
// blocks/CU on this toolchain: R4/R5's 1024-thread variants got capped at 64
// VGPR -> 2.1GB spill traffic). W1a-lo + W3 frags read from global (prep
// kernel) instead of LDS; chunked swizzled cb round-trips; no barriers in the
// 12-pass loop (body verified R4, absmax 4.8e-7).
// ---------------------------------------------------------------------------
__global__ __launch_bounds__(512, 2)
void infl_fused(const float* __restrict__ obs, const float* __restrict__ actions,
                const float* __restrict__ W1, const float* __restrict__ b1,
                const float* __restrict__ b2, const float* __restrict__ b3,
                const _Float16* __restrict__ gfrag, float* __restrict__ out,
                TFKeys keys) {
  // 65536 B total. Prologue: [0,32768) W1-obs-half hi, [32768,65536) lo.
  // Pass loop: [0,16384) w1a_hi, [16384,32768) w2_hi, [32768,49152) w2_lo,
  //            [49152,65536) 8 x 2KB per-wave chunk buffers.
  __shared__ __align__(16) unsigned char smem[65536];
  _Float16* w1oh = (_Float16*)smem;
  _Float16* w1ol = (_Float16*)(smem + 32768);
  _Float16* w1h  = (_Float16*)smem;
  _Float16* w2h  = (_Float16*)(smem + 16384);
  _Float16* w2l  = (_Float16*)(smem + 32768);

  const _Float16* __restrict__ gw1al = gfrag + 8192;
  const _Float16* __restrict__ gw3h  = gfrag + 32768;
  const _Float16* __restrict__ gw3l  = gfrag + 36864;

  const int t = threadIdx.x, wave = t >> 6, lane = t & 63;
  const int R0 = blockIdx.x * 128 + wave * 16;
  const int cA = lane & 15;            // A-row / C-D col
  const int kg = (lane >> 4) << 3;     // k base within 32-k tile
  const int r0 = (lane >> 4) << 2;     // C/D row base
  float* cb = (float*)(smem + 49152 + wave * 2048);   // per-wave [16][32] swizzled

  // ================= prologue: ho = b1 + obs @ W1[0:256] ==================
  f32x4 ho[8];
#pragma unroll
  for (int nt = 0; nt < 8; ++nt) {
    const float bv = b1[nt * 16 + cA];
    ho[nt] = (f32x4){bv, bv, bv, bv};
  }
  {
    const float* orow = obs + (size_t)(R0 + cA) * 256;
    for (int half = 0; half < 2; ++half) {
      __syncthreads();   // previous half's MFMAs done reading frags
      stage_frags<128, 128, 512>(W1 + half * 128 * 128, w1oh, w1ol, t);
      __syncthreads();
#pragma unroll
      for (int kt = 0; kt < 4; ++kt) {
        const float4 va = *(const float4*)(orow + half * 128 + kt * 32 + kg);
        const float4 vb = *(const float4*)(orow + half * 128 + kt * 32 + kg + 4);
        f16x8 oh, ol;
        split44(va, vb, oh, ol);
#pragma unroll
        for (int nt = 0; nt < 8; ++nt) {
          const int tile = kt * 8 + nt;
          const f16x8 bh = *(const f16x8*)&w1oh[(tile * 64 + lane) * 8];
          const f16x8 bl = *(const f16x8*)&w1ol[(tile * 64 + lane) * 8];
          MFMA3(ho[nt], oh, ol, bh, bl)
        }
      }
    }
  }
  __syncthreads();   // prologue reads done; stage pass weights (linear copy)

  {
    const float4* src = (const float4*)gfrag;          // w1a_hi
    float4* dst = (float4*)w1h;
#pragma unroll
    for (int i = 0; i < 2; ++i) dst[t + i * 512] = src[t + i * 512];
    src = (const float4*)(gfrag + 16384);              // w2_hi + w2_lo (32KB)
    dst = (float4*)w2h;
#pragma unroll
    for (int i = 0; i < 4; ++i) dst[t + i * 512] = src[t + i * 512];
  }

  float b2r[4], b3r[4];
#pragma unroll
  for (int nt = 0; nt < 4; ++nt) {
    b2r[nt] = b2[nt * 16 + cA];
    b3r[nt] = b3[nt * 16 + cA];
  }
  __syncthreads();   // last barrier of the kernel

  // ================= MLP body (one pass), chunked round-trips =============
  // h1 in 4 chunks of 32 k: L1 produces 2 tiles -> cb -> L2 partial (kt=c).
  // h2 in 2 chunks of 32 k: -> cb -> L3 (kt=d). Single cb reused; per-wave
  // in-order DS makes WAR safe without barriers (verified R4).
  // W1a-lo and W3 B-frags come straight from global (L1/L2-hot).
#define MLP_BODY(HAS_ACT, acc3)                                              \
  {                                                                          \
    f32x4 a2[4];                                                             \
    _Pragma("unroll") for (int n2 = 0; n2 < 4; ++n2)                         \
      a2[n2] = (f32x4){b2r[n2], b2r[n2], b2r[n2], b2r[n2]};                  \
    _Pragma("unroll") for (int c = 0; c < 4; ++c) {                          \
      f32x4 a10 = ho[2 * c], a11 = ho[2 * c + 1];                            \
      if (HAS_ACT) {                                                         \
        _Pragma("unroll") for (int kt = 0; kt < 2; ++kt) {                   \
          const int t0 = ((kt * 8 + 2 * c) * 64 + lane) * 8;                 \
          const int t1 = ((kt * 8 + 2 * c + 1) * 64 + lane) * 8;             \
          const f16x8 bh0 = *(const f16x8*)&w1h[t0];                         \
          const f16x8 bl0 = *(const f16x8*)&gw1al[t0];                       \
          MFMA3(a10, ah[kt], al[kt], bh0, bl0)                               \
          const f16x8 bh1 = *(const f16x8*)&w1h[t1];                         \
          const f16x8 bl1 = *(const f16x8*)&gw1al[t1];                       \
          MFMA3(a11, ah[kt], al[kt], bh1, bl1)                               \
        }                                                                    \
      }                                                                      \
      _Pragma("unroll") for (int j = 0; j < 4; ++j) {                        \
        cb[swz(r0 + j, cA)]      = fmaxf(a10[j], 0.f);                       \
        cb[swz(r0 + j, 16 + cA)] = fmaxf(a11[j], 0.f);                       \
      }                                                                      \
      const float4 va = *(const float4*)&cb[swz(cA, kg)];                    \
      const float4 vb = *(const float4*)&cb[swz(cA, kg + 4)];                \
      f16x8 hh, hl;                                                          \
      split44(va, vb, hh, hl);                                               \
      _Pragma("unroll") for (int n2 = 0; n2 < 4; ++n2) {                     \
        const int tt = ((c * 4 + n2) * 64 + lane) * 8;                       \
        const f16x8 bh = *(const f16x8*)&w2h[tt];                            \
        const f16x8 bl = *(const f16x8*)&w2l[tt];                            \
        MFMA3(a2[n2], hh, hl, bh, bl)                                        \
      }                                                                      \
    }                                                                        \
    _Pragma("unroll") for (int d = 0; d < 2; ++d) {                          \
      _Pragma("unroll") for (int j = 0; j < 4; ++j) {                        \
        cb[swz(r0 + j, cA)]      = fmaxf(a2[2 * d][j], 0.f);                 \
        cb[swz(r0 + j, 16 + cA)] = fmaxf(a2[2 * d + 1][j], 0.f);             \
      }                                                                      \
      const float4 va = *(const float4*)&cb[swz(cA, kg)];                    \
      const float4 vb = *(const float4*)&cb[swz(cA, kg + 4)];                \
      f16x8 hh, hl;                                                          \
      split44(va, vb, hh, hl);                                               \
      _Pragma("unroll") for (int n3 = 0; n3 < 4; ++n3) {                     \
        const int tt = ((d * 4 + n3) * 64 + lane) * 8;                       \
        const f16x8 bh = *(const f16x8*)&gw3h[tt];                           \
        const f16x8 bl = *(const f16x8*)&gw3l[tt];                           \
        MFMA3(acc3[n3], hh, hl, bh, bl)                                      \
      }                                                                      \
    }                                                                        \
  }

  f32x4 pacc[4];
#pragma unroll
  for (int nt = 0; nt < 4; ++nt) pacc[nt] = (f32x4){0.f, 0.f, 0.f, 0.f};

  // ---- passes 0..10 -> pacc (p=0: zero actions, L1a skipped) ----
  for (int p = 0; p < 11; ++p) {
    f16x8 ah[2], al[2];
    if (p >= 1) {
      const unsigned k0 = keys.k[2 * (p - 1)];
      const unsigned k1 = keys.k[2 * (p - 1) + 1];
      const unsigned base = (unsigned)(R0 + cA) * 64u + (unsigned)kg;
#pragma unroll
      for (int kt = 0; kt < 2; ++kt) {
        float v[8];
#pragma unroll
        for (int e = 0; e < 8; ++e) {
          unsigned o0, o1;
          tf2x32(k0, k1, 0u, base + (unsigned)(kt * 32 + e), o0, o1);
          v[e] = u01(o0 ^ o1);
        }
        split44(*(const float4*)&v[0], *(const float4*)&v[4], ah[kt], al[kt]);
      }
    }
    MLP_BODY(p != 0, pacc)
  }

  // ---- peeled with-actions pass -> pw (short live range) ----
  f32x4 pw[4];
#pragma unroll
  for (int nt = 0; nt < 4; ++nt) pw[nt] = (f32x4){0.f, 0.f, 0.f, 0.f};
  {
    f16x8 ah[2], al[2];
    const float* arow = actions + (size_t)(R0 + cA) * 64 + kg;
#pragma unroll
    for (int kt = 0; kt < 2; ++kt) {
      const float4 va = *(const float4*)(arow + kt * 32);
      const float4 vb = *(const float4*)(arow + kt * 32 + 4);
      split44(va, vb, ah[kt], al[kt]);
    }
    MLP_BODY(true, pw)
  }

  // ---- epilogue: softmax/KL per row, 16-lane shfl reductions ----
  const float inv11 = 1.0f / 11.0f;
#pragma unroll
  for (int j = 0; j < 4; ++j) {
    float pwv[4], pav[4];
#pragma unroll
    for (int nt = 0; nt < 4; ++nt) {
      pwv[nt] = pw[nt][j] + b3r[nt];
      pav[nt] = pacc[nt][j] * inv11 + b3r[nt];
    }
    float mw = fmaxf(fmaxf(pwv[0], pwv[1]), fmaxf(pwv[2], pwv[3]));
    float ma = fmaxf(fmaxf(pav[0], pav[1]), fmaxf(pav[2], pav[3]));
#pragma unroll
    for (int off = 1; off < 16; off <<= 1) {
      mw = fmaxf(mw, __shfl_xor(mw, off, 64));
      ma = fmaxf(ma, __shfl_xor(ma, off, 64));
    }
    float sw = 0.f, sa = 0.f;
#pragma unroll
    for (int nt = 0; nt < 4; ++nt) {
      sw += expf(pwv[nt] - mw);
      sa += expf(pav[nt] - ma);
    }
#pragma unroll
    for (int off = 1; off < 16; off <<= 1) {
      sw += __shfl_xor(sw, off, 64);
      sa += __shfl_xor(sa, off, 64);
    }
    const float lzw = logf(sw), lza = logf(sa);
    float contrib = 0.f;
#pragma unroll
    for (int nt = 0; nt < 4; ++nt) {
      const float lq = pav[nt] - ma - lza;
      const float lp = pwv[nt] - mw - lzw;
      contrib += expf(lq) * (lq - lp);
    }
#pragma unroll
    for (int off = 1; off < 16; off <<= 1)
      contrib += __shfl_xor(contrib, off, 64);
    if (cA == 0) out[R0 + r0 + j] = contrib * (1.0f / 64.0f);
  }
}

extern "C" void kernel_launch(void* const* d_in, const int* in_sizes, int n_in,
                              void* d_out, int out_size, void* d_ws, size_t ws_size,
                              hipStream_t stream) {
  (void)in_sizes; (void)n_in; (void)ws_size; (void)out_size;
  const float* obs     = (const float*)d_in[0];
  const float* actions = (const float*)d_in[1];
  const float* W1      = (const float*)d_in[2];
  const float* b1      = (const float*)d_in[3];
  const float* W2      = (const float*)d_in[4];
  const float* b2      = (const float*)d_in[5];
  const float* W3      = (const float*)d_in[6];
  const float* b3      = (const float*)d_in[7];

  _Float16* gfrag = (_Float16*)d_ws;   // 80KB fragment buffer

  TFKeys keys;
  for (unsigned j = 0; j < NCF; ++j) {
    unsigned o0, o1;
    tf2x32(0u, 42u, 0u, j, o0, o1);
    keys.k[2 * j]     = o0;
    keys.k[2 * j + 1] = o1;
  }

  hipLaunchKernelGGL(prep_frags, dim3(1), dim3(512), 0, stream, W1, W2, W3, gfrag);
  hipLaunchKernelGGL(infl_fused, dim3(1024), dim3(512), 0, stream,
                     obs, actions, W1, b1, b2, b3, (const _Float16*)gfrag,
                     (float*)d_out, keys);
}

// Round 8
// 828.788 us; speedup vs baseline: 1.1872x; 1.1872x over previous
//
#include <hip/hip_runtime.h>
#include <cstddef>

#define NCF 10

struct TFKeys { unsigned k[2 * NCF]; };

typedef __attribute__((ext_vector_type(8))) _Float16 f16x8;
typedef __attribute__((ext_vector_type(4))) float f32x4;

// Threefry-2x32, 20 rounds (JAX-compatible, partitionable semantics verified R1).
__host__ __device__ __forceinline__ void tf2x32(unsigned k0, unsigned k1,
                                                unsigned x0, unsigned x1,
                                                unsigned& o0, unsigned& o1) {
  const unsigned ks2 = k0 ^ k1 ^ 0x1BD11BDAu;
  x0 += k0; x1 += k1;
#define TF_R(r) x0 += x1; x1 = (x1 << (r)) | (x1 >> (32 - (r))); x1 ^= x0;
  TF_R(13) TF_R(15) TF_R(26) TF_R(6)
  x0 += k1;  x1 += ks2 + 1u;
  TF_R(17) TF_R(29) TF_R(16) TF_R(24)
  x0 += ks2; x1 += k0 + 2u;
  TF_R(13) TF_R(15) TF_R(26) TF_R(6)
  x0 += k0;  x1 += k1 + 3u;
  TF_R(17) TF_R(29) TF_R(16) TF_R(24)
  x0 += k1;  x1 += ks2 + 4u;
  TF_R(13) TF_R(15) TF_R(26) TF_R(6)
  x0 += ks2; x1 += k0 + 5u;
#undef TF_R
  o0 = x0; o1 = x1;
}

__device__ __forceinline__ float u01(unsigned bits) {
  return __uint_as_float((bits >> 9) | 0x3f800000u) - 1.0f;
}

// fp16x3 split of 8 floats: x = hi + lo, |x - hi - lo| <= 2^-24 |x|.
__device__ __forceinline__ void split44(const float4 a, const float4 b,
                                        f16x8& hh, f16x8& ll) {
  const float v[8] = {a.x, a.y, a.z, a.w, b.x, b.y, b.z, b.w};
#pragma unroll
  for (int e = 0; e < 8; ++e) {
    const _Float16 h = (_Float16)v[e];
    hh[e] = h;
    ll[e] = (_Float16)(v[e] - (float)h);
  }
}

// D += Ah*Bh + Ah*Bl + Al*Bh  (drops Al*Bl ~ 2^-24)
#define MFMA3(acc, ah, al, bh, bl)                                          \
  acc = __builtin_amdgcn_mfma_f32_16x16x32_f16(ah, bh, acc, 0, 0, 0);       \
  acc = __builtin_amdgcn_mfma_f32_16x16x32_f16(ah, bl, acc, 0, 0, 0);       \
  acc = __builtin_amdgcn_mfma_f32_16x16x32_f16(al, bh, acc, 0, 0, 0);

// Stage W[K][N] (row-major f32) into hi/lo B-fragment layout (verified R2):
// frag elem ((kt*NTN+nt)*64+lane)*8+e  <->  W[kt*32+(lane>>4)*8+e][nt*16+(lane&15)]
template <int K, int N, int NT>
__device__ __forceinline__ void stage_frags(const float* __restrict__ W,
                                            _Float16* fh, _Float16* fl, int t) {
  constexpr int NTN = N / 16;
  for (int i = t; i < K * N; i += NT) {
    const int e = i & 7, lane = (i >> 3) & 63, tile = i >> 9;
    const int kt = tile / NTN, nt = tile % NTN;
    const int k = kt * 32 + ((lane >> 4) << 3) + e;
    const int c = nt * 16 + (lane & 15);
    const float w = W[k * N + c];
    const _Float16 h = (_Float16)w;
    fh[i] = h;
    fl[i] = (_Float16)(w - (float)h);
  }
}

// [16][32] chunk buffer with XOR swizzle: naive layout is a 16-way bank
// conflict on the b128 reads (16 lanes stride 128B); swizzled -> 2-way (free).
__device__ __forceinline__ int swz(int row, int col) {
  return (row << 5) + (col ^ ((row & 7) << 2));
}

// ---------------------------------------------------------------------------
// Fused kernel, 1024 threads = 16 INDEPENDENT waves (16 samples each) sharing
// one 80KB weight-frag copy. Per-wave h round-trips chunked through a 2KB
// swizzled LDS buffer (in-order DS per wave => no barriers in the pass loop).
// LDS 112KB -> 1 block/CU = 16 waves/CU = 4 waves/EU.
// __launch_bounds__(1024, 1): the 2nd arg is CUDA-style MIN BLOCKS/CU on this
// toolchain (fits R2/R3/R4/R6 VGPR evidence): 1 block x 16 waves = 4 waves/EU
// -> 128-VGPR cap. R4's (1024,4) meant 64 waves -> clamped 8/EU -> 64-VGPR cap
// -> 2.1GB spill traffic; R5's waves_per_eu attr was ignored. Body is the
// R4/R5 kernel verbatim (numerically verified, absmax 4.768e-7).
// ---------------------------------------------------------------------------
__global__ __launch_bounds__(1024, 1)
void infl_fused(const float* __restrict__ obs, const float* __restrict__ actions,
                const float* __restrict__ W1, const float* __restrict__ b1,
                const float* __restrict__ W2, const float* __restrict__ b2,
                const float* __restrict__ W3, const float* __restrict__ b3,
                float* __restrict__ out, TFKeys keys) {
  // Prologue: [0,65536) = W1-obs half frags (hi 32KB @0, lo 32KB @32768).
  // Pass loop: [0,81920) = pass-weight frags; [81920,114688) = 16 x 2KB chunk bufs.
  __shared__ __align__(16) unsigned char smem[114688];
  _Float16* w1oh = (_Float16*)smem;
  _Float16* w1ol = (_Float16*)(smem + 32768);
  _Float16* w1h  = (_Float16*)smem;                   // W1-act 64x128 hi (16KB)
  _Float16* w1l  = (_Float16*)(smem + 16384);
  _Float16* w2h  = (_Float16*)(smem + 32768);         // W2 128x64 hi (16KB)
  _Float16* w2l  = (_Float16*)(smem + 49152);
  _Float16* w3h  = (_Float16*)(smem + 65536);         // W3 64x64 hi (8KB)
  _Float16* w3l  = (_Float16*)(smem + 73728);

  const int t = threadIdx.x, wave = t >> 6, lane = t & 63;
  const int R0 = blockIdx.x * 256 + wave * 16;
  const int cA = lane & 15;            // A-row / C-D col
  const int kg = (lane >> 4) << 3;     // k base within 32-k tile
  const int r0 = (lane >> 4) << 2;     // C/D row base
  float* cb = (float*)(smem + 81920 + wave * 2048);   // per-wave [16][32] swizzled

  // ================= prologue: ho = b1 + obs @ W1[0:256] ==================
  f32x4 ho[8];
#pragma unroll
  for (int nt = 0; nt < 8; ++nt) {
    const float bv = b1[nt * 16 + cA];
    ho[nt] = (f32x4){bv, bv, bv, bv};
  }
  {
    const float* orow = obs + (size_t)(R0 + cA) * 256;
    for (int half = 0; half < 2; ++half) {
      __syncthreads();   // previous half's MFMAs done reading frags
      stage_frags<128, 128, 1024>(W1 + half * 128 * 128, w1oh, w1ol, t);
      __syncthreads();
#pragma unroll
      for (int kt = 0; kt < 4; ++kt) {
        const float4 va = *(const float4*)(orow + half * 128 + kt * 32 + kg);
        const float4 vb = *(const float4*)(orow + half * 128 + kt * 32 + kg + 4);
        f16x8 oh, ol;
        split44(va, vb, oh, ol);
#pragma unroll
        for (int nt = 0; nt < 8; ++nt) {
          const int tile = kt * 8 + nt;
          const f16x8 bh = *(const f16x8*)&w1oh[(tile * 64 + lane) * 8];
          const f16x8 bl = *(const f16x8*)&w1ol[(tile * 64 + lane) * 8];
          MFMA3(ho[nt], oh, ol, bh, bl)
        }
      }
    }
  }
  __syncthreads();   // prologue reads done; restage pass weights

  stage_frags<64, 128, 1024>(W1 + 256 * 128, w1h, w1l, t);
  stage_frags<128, 64, 1024>(W2, w2h, w2l, t);
  stage_frags<64, 64, 1024>(W3, w3h, w3l, t);

  float b2r[4], b3r[4];
#pragma unroll
  for (int nt = 0; nt < 4; ++nt) {
    b2r[nt] = b2[nt * 16 + cA];
    b3r[nt] = b3[nt * 16 + cA];
  }
  __syncthreads();   // last barrier of the kernel

  // ================= MLP body (one pass), chunked round-trips =============
  // h1 in 4 chunks of 32 k: L1 produces 2 tiles -> cb -> L2 partial (kt=c).
  // h2 in 2 chunks of 32 k: -> cb -> L3 (kt=d). Single cb reused; per-wave
  // in-order DS makes WAR safe without barriers (verified R4, absmax 4.8e-7).
#define MLP_BODY(HAS_ACT, acc3)                                              \
  {                                                                          \
    f32x4 a2[4];                                                             \
    _Pragma("unroll") for (int n2 = 0; n2 < 4; ++n2)                         \
      a2[n2] = (f32x4){b2r[n2], b2r[n2], b2r[n2], b2r[n2]};                  \
    _Pragma("unroll") for (int c = 0; c < 4; ++c) {                          \
      f32x4 a10 = ho[2 * c], a11 = ho[2 * c + 1];                            \
      if (HAS_ACT) {                                                         \
        _Pragma("unroll") for (int kt = 0; kt < 2; ++kt) {                   \
          const int t0 = ((kt * 8 + 2 * c) * 64 + lane) * 8;                 \
          const int t1 = ((kt * 8 + 2 * c + 1) * 64 + lane) * 8;             \
          const f16x8 bh0 = *(const f16x8*)&w1h[t0];                         \
          const f16x8 bl0 = *(const f16x8*)&w1l[t0];                         \
          MFMA3(a10, ah[kt], al[kt], bh0, bl0)                               \
          const f16x8 bh1 = *(const f16x8*)&w1h[t1];                         \
          const f16x8 bl1 = *(const f16x8*)&w1l[t1];                         \
          MFMA3(a11, ah[kt], al[kt], bh1, bl1)                               \
        }                                                                    \
      }                                                                      \
      _Pragma("unroll") for (int j = 0; j < 4; ++j) {                        \
        cb[swz(r0 + j, cA)]      = fmaxf(a10[j], 0.f);                       \
        cb[swz(r0 + j, 16 + cA)] = fmaxf(a11[j], 0.f);                       \
      }                                                                      \
      const float4 va = *(const float4*)&cb[swz(cA, kg)];                    \
      const float4 vb = *(const float4*)&cb[swz(cA, kg + 4)];                \
      f16x8 hh, hl;                                                          \
      split44(va, vb, hh, hl);                                               \
      _Pragma("unroll") for (int n2 = 0; n2 < 4; ++n2) {                     \
        const int tt = ((c * 4 + n2) * 64 + lane) * 8;                       \
        const f16x8 bh = *(const f16x8*)&w2h[tt];                            \
        const f16x8 bl = *(const f16x8*)&w2l[tt];                            \
        MFMA3(a2[n2], hh, hl, bh, bl)                                        \
      }                                                                      \
    }                                                                        \
    _Pragma("unroll") for (int d = 0; d < 2; ++d) {                          \
      _Pragma("unroll") for (int j = 0; j < 4; ++j) {                        \
        cb[swz(r0 + j, cA)]      = fmaxf(a2[2 * d][j], 0.f);                 \
        cb[swz(r0 + j, 16 + cA)] = fmaxf(a2[2 * d + 1][j], 0.f);             \
      }                                                                      \
      const float4 va = *(const float4*)&cb[swz(cA, kg)];                    \
      const float4 vb = *(const float4*)&cb[swz(cA, kg + 4)];                \
      f16x8 hh, hl;                                                          \
      split44(va, vb, hh, hl);                                               \
      _Pragma("unroll") for (int n3 = 0; n3 < 4; ++n3) {                     \
        const int tt = ((d * 4 + n3) * 64 + lane) * 8;                       \
        const f16x8 bh = *(const f16x8*)&w3h[tt];                            \
        const f16x8 bl = *(const f16x8*)&w3l[tt];                            \
        MFMA3(acc3[n3], hh, hl, bh, bl)                                      \
      }                                                                      \
    }                                                                        \
  }

  f32x4 pacc[4];
#pragma unroll
  for (int nt = 0; nt < 4; ++nt) pacc[nt] = (f32x4){0.f, 0.f, 0.f, 0.f};

  // ---- passes 0..10 -> pacc (p=0: zero actions, L1a skipped) ----
  for (int p = 0; p < 11; ++p) {
    f16x8 ah[2], al[2];
    if (p >= 1) {
      const unsigned k0 = keys.k[2 * (p - 1)];
      const unsigned k1 = keys.k[2 * (p - 1) + 1];
      const unsigned base = (unsigned)(R0 + cA) * 64u + (unsigned)kg;
#pragma unroll
      for (int kt = 0; kt < 2; ++kt) {
        float v[8];
#pragma unroll
        for (int e = 0; e < 8; ++e) {
          unsigned o0, o1;
          tf2x32(k0, k1, 0u, base + (unsigned)(kt * 32 + e), o0, o1);
          v[e] = u01(o0 ^ o1);
        }
        split44(*(const float4*)&v[0], *(const float4*)&v[4], ah[kt], al[kt]);
      }
    }
    MLP_BODY(p != 0, pacc)
  }

  // ---- peeled with-actions pass -> pw (short live range) ----
  f32x4 pw[4];
#pragma unroll
  for (int nt = 0; nt < 4; ++nt) pw[nt] = (f32x4){0.f, 0.f, 0.f, 0.f};
  {
    f16x8 ah[2], al[2];
    const float* arow = actions + (size_t)(R0 + cA) * 64 + kg;
#pragma unroll
    for (int kt = 0; kt < 2; ++kt) {
      const float4 va = *(const float4*)(arow + kt * 32);
      const float4 vb = *(const float4*)(arow + kt * 32 + 4);
      split44(va, vb, ah[kt], al[kt]);
    }
    MLP_BODY(true, pw)
  }

  // ---- epilogue: softmax/KL per row, 16-lane shfl reductions ----
  const float inv11 = 1.0f / 11.0f;
#pragma unroll
  for (int j = 0; j < 4; ++j) {
    float pwv[4], pav[4];
#pragma unroll
    for (int nt = 0; nt < 4; ++nt) {
      pwv[nt] = pw[nt][j] + b3r[nt];
      pav[nt] = pacc[nt][j] * inv11 + b3r[nt];
    }
    float mw = fmaxf(fmaxf(pwv[0], pwv[1]), fmaxf(pwv[2], pwv[3]));
    float ma = fmaxf(fmaxf(pav[0], pav[1]), fmaxf(pav[2], pav[3]));
#pragma unroll
    for (int off = 1; off < 16; off <<= 1) {
      mw = fmaxf(mw, __shfl_xor(mw, off, 64));
      ma = fmaxf(ma, __shfl_xor(ma, off, 64));
    }
    float sw = 0.f, sa = 0.f;
#pragma unroll
    for (int nt = 0; nt < 4; ++nt) {
      sw += expf(pwv[nt] - mw);
      sa += expf(pav[nt] - ma);
    }
#pragma unroll
    for (int off = 1; off < 16; off <<= 1) {
      sw += __shfl_xor(sw, off, 64);
      sa += __shfl_xor(sa, off, 64);
    }
    const float lzw = logf(sw), lza = logf(sa);
    float contrib = 0.f;
#pragma unroll
    for (int nt = 0; nt < 4; ++nt) {
      const float lq = pav[nt] - ma - lza;
      const float lp = pwv[nt] - mw - lzw;
      contrib += expf(lq) * (lq - lp);
    }
#pragma unroll
    for (int off = 1; off < 16; off <<= 1)
      contrib += __shfl_xor(contrib, off, 64);
    if (cA == 0) out[R0 + r0 + j] = contrib * (1.0f / 64.0f);
  }
}

extern "C" void kernel_launch(void* const* d_in, const int* in_sizes, int n_in,
                              void* d_out, int out_size, void* d_ws, size_t ws_size,
                              hipStream_t stream) {
  (void)in_sizes; (void)n_in; (void)d_ws; (void)ws_size; (void)out_size;
  const float* obs     = (const float*)d_in[0];
  const float* actions = (const float*)d_in[1];
  const float* W1      = (const float*)d_in[2];
  const float* b1      = (const float*)d_in[3];
  const float* W2      = (const float*)d_in[4];
  const float* b2      = (const float*)d_in[5];
  const float* W3      = (const float*)d_in[6];
  const float* b3      = (const float*)d_in[7];

  TFKeys keys;
  for (unsigned j = 0; j < NCF; ++j) {
    unsigned o0, o1;
    tf2x32(0u, 42u, 0u, j, o0, o1);
    keys.k[2 * j]     = o0;
    keys.k[2 * j + 1] = o1;
  }

  hipLaunchKernelGGL(infl_fused, dim3(512), dim3(1024), 0, stream,
                     obs, actions, W1, b1, W2, b2, W3, b3, (float*)d_out, keys);
}

// Round 9
// 724.030 us; speedup vs baseline: 1.3590x; 1.1447x over previous
//
#include <hip/hip_runtime.h>
#include <cstddef>

#define NCF 10

struct TFKeys { unsigned k[2 * NCF]; };

typedef __attribute__((ext_vector_type(8))) _Float16 f16x8;
typedef __attribute__((ext_vector_type(4))) float f32x4;

// Threefry-2x32, 20 rounds (JAX-compatible, partitionable semantics verified R1).
__host__ __device__ __forceinline__ void tf2x32(unsigned k0, unsigned k1,
                                                unsigned x0, unsigned x1,
                                                unsigned& o0, unsigned& o1) {
  const unsigned ks2 = k0 ^ k1 ^ 0x1BD11BDAu;
  x0 += k0; x1 += k1;
#define TF_R(r) x0 += x1; x1 = (x1 << (r)) | (x1 >> (32 - (r))); x1 ^= x0;
  TF_R(13) TF_R(15) TF_R(26) TF_R(6)
  x0 += k1;  x1 += ks2 + 1u;
  TF_R(17) TF_R(29) TF_R(16) TF_R(24)
  x0 += ks2; x1 += k0 + 2u;
  TF_R(13) TF_R(15) TF_R(26) TF_R(6)
  x0 += k0;  x1 += k1 + 3u;
  TF_R(17) TF_R(29) TF_R(16) TF_R(24)
  x0 += k1;  x1 += ks2 + 4u;
  TF_R(13) TF_R(15) TF_R(26) TF_R(6)
  x0 += ks2; x1 += k0 + 5u;
#undef TF_R
  o0 = x0; o1 = x1;
}

__device__ __forceinline__ float u01(unsigned bits) {
  return __uint_as_float((bits >> 9) | 0x3f800000u) - 1.0f;
}

// fp16x3 split of 8 floats: x = hi + lo, |x - hi - lo| <= 2^-24 |x|.
__device__ __forceinline__ void split44(const float4 a, const float4 b,
                                        f16x8& hh, f16x8& ll) {
  const float v[8] = {a.x, a.y, a.z, a.w, b.x, b.y, b.z, b.w};
#pragma unroll
  for (int e = 0; e < 8; ++e) {
    const _Float16 h = (_Float16)v[e];
    hh[e] = h;
    ll[e] = (_Float16)(v[e] - (float)h);
  }
}

// D += Ah*Bh + Ah*Bl + Al*Bh (drops Al*Bl ~ 2^-24). Here A = weight frags.
#define MFMA3(acc, ah, al, bh, bl)                                          \
  acc = __builtin_amdgcn_mfma_f32_16x16x32_f16(ah, bh, acc, 0, 0, 0);       \
  acc = __builtin_amdgcn_mfma_f32_16x16x32_f16(ah, bl, acc, 0, 0, 0);       \
  acc = __builtin_amdgcn_mfma_f32_16x16x32_f16(al, bh, acc, 0, 0, 0);

// Stage W[K][N] (row-major f32) into hi/lo fragment layout (verified R2).
// frag elem ((kt*NTN+nt)*64+lane)*8+e <-> W[kt*32+(lane>>4)*8+e][nt*16+(lane&15)]
// NOTE: A-frag (row=lane&15, k=8q+e) and B-frag (col=lane&15, k=8q+e) have the
// SAME (lane,e) map, so this layout serves as W^T A-operand unchanged.
template <int K, int N>
__device__ __forceinline__ void stage_frags(const float* __restrict__ W,
                                            _Float16* fh, _Float16* fl, int t) {
  constexpr int NTN = N / 16;
  for (int i = t; i < K * N; i += 512) {
    const int e = i & 7, lane = (i >> 3) & 63, tile = i >> 9;
    const int kt = tile / NTN, nt = tile % NTN;
    const int k = kt * 32 + ((lane >> 4) << 3) + e;
    const int c = nt * 16 + (lane & 15);
    const float w = W[k * N + c];
    const _Float16 h = (_Float16)w;
    fh[i] = h;
    fl[i] = (_Float16)(w - (float)h);
  }
}

// Swapped-orientation transpose: D-layout [feat][samp] tiles T0 (feats 0-15),
// T1 (feats 16-31) -> B-frag av[e] = h[8q+e][cA]. Source lane and published
// register are uniform per e (derivation verified on 4 concrete cases, R9):
//   src lane = (2(q&1) + (e>>2))<<4 | cA, published reg = T?[e&3], tile = q>>1.
__device__ __forceinline__ void xposeT(const f32x4 T0, const f32x4 T1,
                                       const int src0, const int src1,
                                       const bool tsel, float* av) {
#pragma unroll
  for (int e = 0; e < 8; ++e) {
    const int j = e & 3;
    const int s = (e < 4) ? src0 : src1;
    const float p0 = __shfl(T0[j], s, 64);
    const float p1 = __shfl(T1[j], s, 64);
    av[e] = tsel ? p1 : p0;
  }
}

// ---------------------------------------------------------------------------
// Fused kernel, SWAPPED orientation: every GEMM computes W^T · x^T so the
// layer-to-layer transpose is a 16-shfl register shuffle -> ZERO activation
// LDS. LDS = exactly 80KB of weight frags -> 2 blocks/CU = 16 waves/CU =
// 4 waves/EU (512-thread blocks: the only shape this toolchain gives 128
// VGPRs; 1024-thread blocks are hard-capped at 64 -> spills, R4/R5/R8).
// No barriers and no global loads in the 12-pass loop.
// ---------------------------------------------------------------------------
__global__ __launch_bounds__(512, 2)
void infl_fused(const float* __restrict__ obs, const float* __restrict__ actions,
                const float* __restrict__ W1, const float* __restrict__ b1,
                const float* __restrict__ W2, const float* __restrict__ b2,
                const float* __restrict__ W3, const float* __restrict__ b3,
                float* __restrict__ out, TFKeys keys) {
  // 81920 B. Prologue: [0,32768) W1-obs-half hi, [32768,65536) lo.
  // Pass loop: [0)w1a_hi [16384)w1a_lo [32768)w2_hi [49152)w2_lo
  //            [65536)w3_hi [73728)w3_lo.  2 x 81920 = 163840 = full CU LDS.
  __shared__ __align__(16) unsigned char smem[81920];
  _Float16* w1oh = (_Float16*)smem;
  _Float16* w1ol = (_Float16*)(smem + 32768);
  _Float16* w1h  = (_Float16*)smem;
  _Float16* w1l  = (_Float16*)(smem + 16384);
  _Float16* w2h  = (_Float16*)(smem + 32768);
  _Float16* w2l  = (_Float16*)(smem + 49152);
  _Float16* w3h  = (_Float16*)(smem + 65536);
  _Float16* w3l  = (_Float16*)(smem + 73728);

  const int t = threadIdx.x, wave = t >> 6, lane = t & 63;
  const int R0 = blockIdx.x * 128 + wave * 16;
  const int cA = lane & 15;            // sample (B-col / D-col)
  const int q  = lane >> 4;
  const int kg = q << 3;               // k base within 32-k tile
  const int r0 = q << 2;               // D row base (feature offset)
  // xposeT lane constants
  const int src0 = ((2 * (q & 1)) << 4) + cA;       // e<4  (b=0)
  const int src1 = ((2 * (q & 1) + 1) << 4) + cA;   // e>=4 (b=1)
  const bool tsel = (q >> 1) != 0;

  // ========== prologue: ho[feat][samp] = b1 + W1[0:256]^T @ obs^T ==========
  f32x4 ho[8];
#pragma unroll
  for (int nt = 0; nt < 8; ++nt)
    ho[nt] = *(const f32x4*)(b1 + nt * 16 + r0);    // per-row bias fold
  {
    const float* orow = obs + (size_t)(R0 + cA) * 256;
    for (int half = 0; half < 2; ++half) {
      __syncthreads();   // previous half's MFMAs done reading frags
      stage_frags<128, 128>(W1 + half * 128 * 128, w1oh, w1ol, t);
      __syncthreads();
#pragma unroll
      for (int kt = 0; kt < 4; ++kt) {
        const float4 va = *(const float4*)(orow + half * 128 + kt * 32 + kg);
        const float4 vb = *(const float4*)(orow + half * 128 + kt * 32 + kg + 4);
        f16x8 oh, ol;
        split44(va, vb, oh, ol);
#pragma unroll
        for (int nt = 0; nt < 8; ++nt) {
          const int tile = kt * 8 + nt;
          const f16x8 wh = *(const f16x8*)&w1oh[(tile * 64 + lane) * 8];
          const f16x8 wl = *(const f16x8*)&w1ol[(tile * 64 + lane) * 8];
          MFMA3(ho[nt], wh, wl, oh, ol)
        }
      }
    }
  }
  __syncthreads();   // prologue reads done; restage pass weights

  stage_frags<64, 128>(W1 + 256 * 128, w1h, w1l, t);
  stage_frags<128, 64>(W2, w2h, w2l, t);
  stage_frags<64, 64>(W3, w3h, w3l, t);

  f32x4 b2r[4];
#pragma unroll
  for (int n2 = 0; n2 < 4; ++n2)
    b2r[n2] = *(const f32x4*)(b2 + n2 * 16 + r0);
  __syncthreads();   // last barrier of the kernel

  // ================= MLP body (one pass), swapped orientation =============
  // L1: a1[feat-tile] = ho (+ W1a^T @ act^T); relu; xposeT -> B-frag
  // L2: a2 += W2^T-slab @ h1-frag (4 slabs); +b2; relu; xposeT
  // L3: acc3 += W3^T-slab @ h2-frag (2 slabs)
#define MLP_BODY(HAS_ACT, acc3)                                              \
  {                                                                          \
    f32x4 a2[4];                                                             \
    _Pragma("unroll") for (int n2 = 0; n2 < 4; ++n2) a2[n2] = b2r[n2];       \
    _Pragma("unroll") for (int c = 0; c < 4; ++c) {                          \
      f32x4 a10 = ho[2 * c], a11 = ho[2 * c + 1];                            \
      if (HAS_ACT) {                                                         \
        _Pragma("unroll") for (int kt = 0; kt < 2; ++kt) {                   \
          const int t0 = ((kt * 8 + 2 * c) * 64 + lane) * 8;                 \
          const int t1 = ((kt * 8 + 2 * c + 1) * 64 + lane) * 8;             \
          const f16x8 wh0 = *(const f16x8*)&w1h[t0];                         \
          const f16x8 wl0 = *(const f16x8*)&w1l[t0];                         \
          MFMA3(a10, wh0, wl0, ah[kt], al[kt])                               \
          const f16x8 wh1 = *(const f16x8*)&w1h[t1];                         \
          const f16x8 wl1 = *(const f16x8*)&w1l[t1];                         \
          MFMA3(a11, wh1, wl1, ah[kt], al[kt])                               \
        }                                                                    \
      }                                                                      \
      _Pragma("unroll") for (int j = 0; j < 4; ++j) {                        \
        a10[j] = fmaxf(a10[j], 0.f);                                         \
        a11[j] = fmaxf(a11[j], 0.f);                                         \
      }                                                                      \
      float av[8];                                                           \
      xposeT(a10, a11, src0, src1, tsel, av);                                \
      f16x8 hh, hl;                                                          \
      split44(*(const float4*)&av[0], *(const float4*)&av[4], hh, hl);       \
      _Pragma("unroll") for (int n2 = 0; n2 < 4; ++n2) {                     \
        const int tt = ((c * 4 + n2) * 64 + lane) * 8;                       \
        const f16x8 wh = *(const f16x8*)&w2h[tt];                            \
        const f16x8 wl = *(const f16x8*)&w2l[tt];                            \
        MFMA3(a2[n2], wh, wl, hh, hl)                                        \
      }                                                                      \
    }                                                                        \
    _Pragma("unroll") for (int d = 0; d < 2; ++d) {                          \
      f32x4 h20 = a2[2 * d], h21 = a2[2 * d + 1];                            \
      _Pragma("unroll") for (int j = 0; j < 4; ++j) {                        \
        h20[j] = fmaxf(h20[j], 0.f);                                         \
        h21[j] = fmaxf(h21[j], 0.f);                                         \
      }                                                                      \
      float av[8];                                                           \
      xposeT(h20, h21, src0, src1, tsel, av);                                \
      f16x8 hh, hl;                                                          \
      split44(*(const float4*)&av[0], *(const float4*)&av[4], hh, hl);       \
      _Pragma("unroll") for (int n3 = 0; n3 < 4; ++n3) {                     \
        const int tt = ((d * 4 + n3) * 64 + lane) * 8;                       \
        const f16x8 wh = *(const f16x8*)&w3h[tt];                            \
        const f16x8 wl = *(const f16x8*)&w3l[tt];                            \
        MFMA3(acc3[n3], wh, wl, hh, hl)                                      \
      }                                                                      \
    }                                                                        \
  }

  f32x4 pacc[4];
#pragma unroll
  for (int nt = 0; nt < 4; ++nt) pacc[nt] = (f32x4){0.f, 0.f, 0.f, 0.f};

  // ---- passes 0..10 -> pacc (p=0: zero actions, L1a skipped) ----
  for (int p = 0; p < 11; ++p) {
    f16x8 ah[2], al[2];
    if (p >= 1) {
      const unsigned k0 = keys.k[2 * (p - 1)];
      const unsigned k1 = keys.k[2 * (p - 1) + 1];
      const unsigned base = (unsigned)(R0 + cA) * 64u + (unsigned)kg;
#pragma unroll
      for (int kt = 0; kt < 2; ++kt) {
        float v[8];
#pragma unroll
        for (int e = 0; e < 8; ++e) {
          unsigned o0, o1;
          tf2x32(k0, k1, 0u, base + (unsigned)(kt * 32 + e), o0, o1);
          v[e] = u01(o0 ^ o1);
        }
        split44(*(const float4*)&v[0], *(const float4*)&v[4], ah[kt], al[kt]);
      }
    }
    MLP_BODY(p != 0, pacc)
  }

  // ---- peeled with-actions pass -> pw (short live range) ----
  f32x4 pw[4];
#pragma unroll
  for (int nt = 0; nt < 4; ++nt) pw[nt] = (f32x4){0.f, 0.f, 0.f, 0.f};
  {
    f16x8 ah[2], al[2];
    const float* arow = actions + (size_t)(R0 + cA) * 64 + kg;
#pragma unroll
    for (int kt = 0; kt < 2; ++kt) {
      const float4 va = *(const float4*)(arow + kt * 32);
      const float4 vb = *(const float4*)(arow + kt * 32 + 4);
      split44(va, vb, ah[kt], al[kt]);
    }
    MLP_BODY(true, pw)
  }

  // ---- epilogue: lane holds 16 of 64 logits for sample cA; reduce over the
  // 4 q-groups (xor 16, 32). One softmax/KL per sample, lanes 0-15 write. ----
  const float inv11 = 1.0f / 11.0f;
  f32x4 b3r[4];
#pragma unroll
  for (int n3 = 0; n3 < 4; ++n3)
    b3r[n3] = *(const f32x4*)(b3 + n3 * 16 + r0);

  float pwv[16], pav[16];
#pragma unroll
  for (int n3 = 0; n3 < 4; ++n3)
#pragma unroll
    for (int j = 0; j < 4; ++j) {
      pwv[n3 * 4 + j] = pw[n3][j] + b3r[n3][j];
      pav[n3 * 4 + j] = pacc[n3][j] * inv11 + b3r[n3][j];
    }
  float mw = pwv[0], ma = pav[0];
#pragma unroll
  for (int i = 1; i < 16; ++i) {
    mw = fmaxf(mw, pwv[i]);
    ma = fmaxf(ma, pav[i]);
  }
  mw = fmaxf(mw, __shfl_xor(mw, 16, 64));
  mw = fmaxf(mw, __shfl_xor(mw, 32, 64));
  ma = fmaxf(ma, __shfl_xor(ma, 16, 64));
  ma = fmaxf(ma, __shfl_xor(ma, 32, 64));
  float sw = 0.f, sa = 0.f;
#pragma unroll
  for (int i = 0; i < 16; ++i) {
    sw += expf(pwv[i] - mw);
    sa += expf(pav[i] - ma);
  }
  sw += __shfl_xor(sw, 16, 64); sw += __shfl_xor(sw, 32, 64);
  sa += __shfl_xor(sa, 16, 64); sa += __shfl_xor(sa, 32, 64);
  const float lzw = logf(sw), lza = logf(sa);
  float contrib = 0.f;
#pragma unroll
  for (int i = 0; i < 16; ++i) {
    const float lq = pav[i] - ma - lza;
    const float lp = pwv[i] - mw - lzw;
    contrib += expf(lq) * (lq - lp);
  }
  contrib += __shfl_xor(contrib, 16, 64);
  contrib += __shfl_xor(contrib, 32, 64);
  if (lane < 16) out[R0 + cA] = contrib * (1.0f / 64.0f);
}

extern "C" void kernel_launch(void* const* d_in, const int* in_sizes, int n_in,
                              void* d_out, int out_size, void* d_ws, size_t ws_size,
                              hipStream_t stream) {
  (void)in_sizes; (void)n_in; (void)d_ws; (void)ws_size; (void)out_size;
  const float* obs     = (const float*)d_in[0];
  const float* actions = (const float*)d_in[1];
  const float* W1      = (const float*)d_in[2];
  const float* b1      = (const float*)d_in[3];
  const float* W2      = (const float*)d_in[4];
  const float* b2      = (const float*)d_in[5];
  const float* W3      = (const float*)d_in[6];
  const float* b3      = (const float*)d_in[7];

  TFKeys keys;
  for (unsigned j = 0; j < NCF; ++j) {
    unsigned o0, o1;
    tf2x32(0u, 42u, 0u, j, o0, o1);
    keys.k[2 * j]     = o0;
    keys.k[2 * j + 1] = o1;
  }

  hipLaunchKernelGGL(infl_fused, dim3(1024), dim3(512), 0, stream,
                     obs, actions, W1, b1, W2, b2, W3, b3, (float*)d_out, keys);
}

// Round 10
// 676.250 us; speedup vs baseline: 1.4550x; 1.0707x over previous
//
#include <hip/hip_runtime.h>
#include <cstddef>

#define NCF 10

struct TFKeys { unsigned k[2 * NCF]; };

typedef __attribute__((ext_vector_type(8))) _Float16 f16x8;
typedef __attribute__((ext_vector_type(4))) float f32x4;

// Threefry-2x32, 20 rounds (JAX-compatible, partitionable semantics verified R1).
__host__ __device__ __forceinline__ void tf2x32(unsigned k0, unsigned k1,
                                                unsigned x0, unsigned x1,
                                                unsigned& o0, unsigned& o1) {
  const unsigned ks2 = k0 ^ k1 ^ 0x1BD11BDAu;
  x0 += k0; x1 += k1;
#define TF_R(r) x0 += x1; x1 = (x1 << (r)) | (x1 >> (32 - (r))); x1 ^= x0;
  TF_R(13) TF_R(15) TF_R(26) TF_R(6)
  x0 += k1;  x1 += ks2 + 1u;
  TF_R(17) TF_R(29) TF_R(16) TF_R(24)
  x0 += ks2; x1 += k0 + 2u;
  TF_R(13) TF_R(15) TF_R(26) TF_R(6)
  x0 += k0;  x1 += k1 + 3u;
  TF_R(17) TF_R(29) TF_R(16) TF_R(24)
  x0 += k1;  x1 += ks2 + 4u;
  TF_R(13) TF_R(15) TF_R(26) TF_R(6)
  x0 += ks2; x1 += k0 + 5u;
#undef TF_R
  o0 = x0; o1 = x1;
}

__device__ __forceinline__ float u01(unsigned bits) {
  return __uint_as_float((bits >> 9) | 0x3f800000u) - 1.0f;
}

// fp16x3 split of 8 floats: x = hi + lo, |x - hi - lo| <= 2^-24 |x|.
__device__ __forceinline__ void split44(const float4 a, const float4 b,
                                        f16x8& hh, f16x8& ll) {
  const float v[8] = {a.x, a.y, a.z, a.w, b.x, b.y, b.z, b.w};
#pragma unroll
  for (int e = 0; e < 8; ++e) {
    const _Float16 h = (_Float16)v[e];
    hh[e] = h;
    ll[e] = (_Float16)(v[e] - (float)h);
  }
}

// D += Ah*Bh + Ah*Bl + Al*Bh (drops Al*Bl ~ 2^-24). Here A = weight frags.
#define MFMA3(acc, ah, al, bh, bl)                                          \
  acc = __builtin_amdgcn_mfma_f32_16x16x32_f16(ah, bh, acc, 0, 0, 0);       \
  acc = __builtin_amdgcn_mfma_f32_16x16x32_f16(ah, bl, acc, 0, 0, 0);       \
  acc = __builtin_amdgcn_mfma_f32_16x16x32_f16(al, bh, acc, 0, 0, 0);

// Stage W[K][N] (row-major f32) into hi/lo fragment layout (verified R2).
// frag elem ((kt*NTN+nt)*64+lane)*8+e <-> W[kt*32+(lane>>4)*8+e][nt*16+(lane&15)]
template <int K, int N>
__device__ __forceinline__ void stage_frags(const float* __restrict__ W,
                                            _Float16* fh, _Float16* fl, int t) {
  constexpr int NTN = N / 16;
  for (int i = t; i < K * N; i += 512) {
    const int e = i & 7, lane = (i >> 3) & 63, tile = i >> 9;
    const int kt = tile / NTN, nt = tile % NTN;
    const int k = kt * 32 + ((lane >> 4) << 3) + e;
    const int c = nt * 16 + (lane & 15);
    const float w = W[k * N + c];
    const _Float16 h = (_Float16)w;
    fh[i] = h;
    fl[i] = (_Float16)(w - (float)h);
  }
}

// Swapped-orientation transpose (verified R9, absmax 4.77e-7): D-layout
// [feat][samp] tiles T0/T1 -> B-frag av[e] = h[8q+e][cA].
__device__ __forceinline__ void xposeT(const f32x4 T0, const f32x4 T1,
                                       const int src0, const int src1,
                                       const bool tsel, float* av) {
#pragma unroll
  for (int e = 0; e < 8; ++e) {
    const int j = e & 3;
    const int s = (e < 4) ? src0 : src1;
    const float p0 = __shfl(T0[j], s, 64);
    const float p1 = __shfl(T1[j], s, 64);
    av[e] = tsel ? p1 : p0;
  }
}

// ---------------------------------------------------------------------------
// Fused kernel, swapped orientation (R9 lineage). Register-diet revision:
// the with-actions pass runs FIRST and its logits are parked in d_ws (33.5MB,
// written once / reloaded once in the epilogue), removing 16 persistent VGPRs
// from the 11-pass loop. Goal: true VGPR demand <= ~120 so two 512-thread
// blocks (16 waves x ~120 = ~1920 regs < 2048 pool) can co-reside per CU
// (R6/R9 failed at exactly 128 x 16 = 2048 = full pool). LDS = 80KB weight
// frags only; no barriers / no global weight loads in the pass loop.
// ---------------------------------------------------------------------------
__global__ __launch_bounds__(512, 2)
void infl_fused(const float* __restrict__ obs, const float* __restrict__ actions,
                const float* __restrict__ W1, const float* __restrict__ b1,
                const float* __restrict__ W2, const float* __restrict__ b2,
                const float* __restrict__ W3, const float* __restrict__ b3,
                float* __restrict__ pwbuf, float* __restrict__ out, TFKeys keys) {
  // 81920 B. Prologue: [0,32768) W1-obs-half hi, [32768,65536) lo.
  // Pass loop: [0)w1a_hi [16384)w1a_lo [32768)w2_hi [49152)w2_lo
  //            [65536)w3_hi [73728)w3_lo.
  __shared__ __align__(16) unsigned char smem[81920];
  _Float16* w1oh = (_Float16*)smem;
  _Float16* w1ol = (_Float16*)(smem + 32768);
  _Float16* w1h  = (_Float16*)smem;
  _Float16* w1l  = (_Float16*)(smem + 16384);
  _Float16* w2h  = (_Float16*)(smem + 32768);
  _Float16* w2l  = (_Float16*)(smem + 49152);
  _Float16* w3h  = (_Float16*)(smem + 65536);
  _Float16* w3l  = (_Float16*)(smem + 73728);

  const int t = threadIdx.x, wave = t >> 6, lane = t & 63;
  const int R0 = blockIdx.x * 128 + wave * 16;
  const int cA = lane & 15;            // sample (B-col / D-col)
  const int q  = lane >> 4;
  const int kg = q << 3;               // k base within 32-k tile
  const int r0 = q << 2;               // D row base (feature offset)
  const int src0 = ((2 * (q & 1)) << 4) + cA;
  const int src1 = ((2 * (q & 1) + 1) << 4) + cA;
  const bool tsel = (q >> 1) != 0;

  // ========== prologue: ho[feat][samp] = b1 + W1[0:256]^T @ obs^T ==========
  f32x4 ho[8];
#pragma unroll
  for (int nt = 0; nt < 8; ++nt)
    ho[nt] = *(const f32x4*)(b1 + nt * 16 + r0);
  {
    const float* orow = obs + (size_t)(R0 + cA) * 256;
    for (int half = 0; half < 2; ++half) {
      __syncthreads();   // previous half's MFMAs done reading frags
      stage_frags<128, 128>(W1 + half * 128 * 128, w1oh, w1ol, t);
      __syncthreads();
#pragma unroll
      for (int kt = 0; kt < 4; ++kt) {
        const float4 va = *(const float4*)(orow + half * 128 + kt * 32 + kg);
        const float4 vb = *(const float4*)(orow + half * 128 + kt * 32 + kg + 4);
        f16x8 oh, ol;
        split44(va, vb, oh, ol);
#pragma unroll
        for (int nt = 0; nt < 8; ++nt) {
          const int tile = kt * 8 + nt;
          const f16x8 wh = *(const f16x8*)&w1oh[(tile * 64 + lane) * 8];
          const f16x8 wl = *(const f16x8*)&w1ol[(tile * 64 + lane) * 8];
          MFMA3(ho[nt], wh, wl, oh, ol)
        }
      }
    }
  }
  __syncthreads();   // prologue reads done; restage pass weights

  stage_frags<64, 128>(W1 + 256 * 128, w1h, w1l, t);
  stage_frags<128, 64>(W2, w2h, w2l, t);
  stage_frags<64, 64>(W3, w3h, w3l, t);

  f32x4 b2r[4];
#pragma unroll
  for (int n2 = 0; n2 < 4; ++n2)
    b2r[n2] = *(const f32x4*)(b2 + n2 * 16 + r0);
  __syncthreads();   // last barrier of the kernel

  // ================= MLP body (one pass), swapped orientation =============
#define MLP_BODY(HAS_ACT, acc3)                                              \
  {                                                                          \
    f32x4 a2[4];                                                             \
    _Pragma("unroll") for (int n2 = 0; n2 < 4; ++n2) a2[n2] = b2r[n2];       \
    _Pragma("unroll") for (int c = 0; c < 4; ++c) {                          \
      f32x4 a10 = ho[2 * c], a11 = ho[2 * c + 1];                            \
      if (HAS_ACT) {                                                         \
        _Pragma("unroll") for (int kt = 0; kt < 2; ++kt) {                   \
          const int t0 = ((kt * 8 + 2 * c) * 64 + lane) * 8;                 \
          const int t1 = ((kt * 8 + 2 * c + 1) * 64 + lane) * 8;             \
          const f16x8 wh0 = *(const f16x8*)&w1h[t0];                         \
          const f16x8 wl0 = *(const f16x8*)&w1l[t0];                         \
          MFMA3(a10, wh0, wl0, ah[kt], al[kt])                               \
          const f16x8 wh1 = *(const f16x8*)&w1h[t1];                         \
          const f16x8 wl1 = *(const f16x8*)&w1l[t1];                         \
          MFMA3(a11, wh1, wl1, ah[kt], al[kt])                               \
        }                                                                    \
      }                                                                      \
      _Pragma("unroll") for (int j = 0; j < 4; ++j) {                        \
        a10[j] = fmaxf(a10[j], 0.f);                                         \
        a11[j] = fmaxf(a11[j], 0.f);                                         \
      }                                                                      \
      float av[8];                                                           \
      xposeT(a10, a11, src0, src1, tsel, av);                                \
      f16x8 hh, hl;                                                          \
      split44(*(const float4*)&av[0], *(const float4*)&av[4], hh, hl);       \
      _Pragma("unroll") for (int n2 = 0; n2 < 4; ++n2) {                     \
        const int tt = ((c * 4 + n2) * 64 + lane) * 8;                       \
        const f16x8 wh = *(const f16x8*)&w2h[tt];                            \
        const f16x8 wl = *(const f16x8*)&w2l[tt];                            \
        MFMA3(a2[n2], wh, wl, hh, hl)                                        \
      }                                                                      \
    }                                                                        \
    _Pragma("unroll") for (int d = 0; d < 2; ++d) {                          \
      f32x4 h20 = a2[2 * d], h21 = a2[2 * d + 1];                            \
      _Pragma("unroll") for (int j = 0; j < 4; ++j) {                        \
        h20[j] = fmaxf(h20[j], 0.f);                                         \
        h21[j] = fmaxf(h21[j], 0.f);                                         \
      }                                                                      \
      float av[8];                                                           \
      xposeT(h20, h21, src0, src1, tsel, av);                                \
      f16x8 hh, hl;                                                          \
      split44(*(const float4*)&av[0], *(const float4*)&av[4], hh, hl);       \
      _Pragma("unroll") for (int n3 = 0; n3 < 4; ++n3) {                     \
        const int tt = ((d * 4 + n3) * 64 + lane) * 8;                       \
        const f16x8 wh = *(const f16x8*)&w3h[tt];                            \
        const f16x8 wl = *(const f16x8*)&w3l[tt];                            \
        MFMA3(acc3[n3], wh, wl, hh, hl)                                      \
      }                                                                      \
    }                                                                        \
  }

  // ---- with-actions pass FIRST -> pw -> parked in pwbuf (d_ws) ----
  {
    f16x8 ah[2], al[2];
    const float* arow = actions + (size_t)(R0 + cA) * 64 + kg;
#pragma unroll
    for (int kt = 0; kt < 2; ++kt) {
      const float4 va = *(const float4*)(arow + kt * 32);
      const float4 vb = *(const float4*)(arow + kt * 32 + 4);
      split44(va, vb, ah[kt], al[kt]);
    }
    f32x4 pw[4];
#pragma unroll
    for (int nt = 0; nt < 4; ++nt) pw[nt] = (f32x4){0.f, 0.f, 0.f, 0.f};
    MLP_BODY(true, pw)
    float* dst = pwbuf + (size_t)(R0 + cA) * 64 + r0;
#pragma unroll
    for (int n3 = 0; n3 < 4; ++n3)
      *(f32x4*)(dst + n3 * 16) = pw[n3];
  }

  // ---- passes 0..10 -> pacc (p=0: zero actions, L1a skipped) ----
  f32x4 pacc[4];
#pragma unroll
  for (int nt = 0; nt < 4; ++nt) pacc[nt] = (f32x4){0.f, 0.f, 0.f, 0.f};

  for (int p = 0; p < 11; ++p) {
    f16x8 ah[2], al[2];
    if (p >= 1) {
      const unsigned k0 = keys.k[2 * (p - 1)];
      const unsigned k1 = keys.k[2 * (p - 1) + 1];
      const unsigned base = (unsigned)(R0 + cA) * 64u + (unsigned)kg;
#pragma unroll
      for (int kt = 0; kt < 2; ++kt) {
        float v[8];
#pragma unroll
        for (int e = 0; e < 8; ++e) {
          unsigned o0, o1;
          tf2x32(k0, k1, 0u, base + (unsigned)(kt * 32 + e), o0, o1);
          v[e] = u01(o0 ^ o1);
        }
        split44(*(const float4*)&v[0], *(const float4*)&v[4], ah[kt], al[kt]);
      }
    }
    MLP_BODY(p != 0, pacc)
  }

  // ---- epilogue: reload pw; lane holds 16 of 64 logits for sample cA ----
  const float inv11 = 1.0f / 11.0f;
  f32x4 b3r[4], pwr[4];
#pragma unroll
  for (int n3 = 0; n3 < 4; ++n3) {
    b3r[n3] = *(const f32x4*)(b3 + n3 * 16 + r0);
    pwr[n3] = *(const f32x4*)(pwbuf + (size_t)(R0 + cA) * 64 + n3 * 16 + r0);
  }

  float pwv[16], pav[16];
#pragma unroll
  for (int n3 = 0; n3 < 4; ++n3)
#pragma unroll
    for (int j = 0; j < 4; ++j) {
      pwv[n3 * 4 + j] = pwr[n3][j] + b3r[n3][j];
      pav[n3 * 4 + j] = pacc[n3][j] * inv11 + b3r[n3][j];
    }
  float mw = pwv[0], ma = pav[0];
#pragma unroll
  for (int i = 1; i < 16; ++i) {
    mw = fmaxf(mw, pwv[i]);
    ma = fmaxf(ma, pav[i]);
  }
  mw = fmaxf(mw, __shfl_xor(mw, 16, 64));
  mw = fmaxf(mw, __shfl_xor(mw, 32, 64));
  ma = fmaxf(ma, __shfl_xor(ma, 16, 64));
  ma = fmaxf(ma, __shfl_xor(ma, 32, 64));
  float sw = 0.f, sa = 0.f;
#pragma unroll
  for (int i = 0; i < 16; ++i) {
    sw += expf(pwv[i] - mw);
    sa += expf(pav[i] - ma);
  }
  sw += __shfl_xor(sw, 16, 64); sw += __shfl_xor(sw, 32, 64);
  sa += __shfl_xor(sa, 16, 64); sa += __shfl_xor(sa, 32, 64);
  const float lzw = logf(sw), lza = logf(sa);
  float contrib = 0.f;
#pragma unroll
  for (int i = 0; i < 16; ++i) {
    const float lq = pav[i] - ma - lza;
    const float lp = pwv[i] - mw - lzw;
    contrib += expf(lq) * (lq - lp);
  }
  contrib += __shfl_xor(contrib, 16, 64);
  contrib += __shfl_xor(contrib, 32, 64);
  if (lane < 16) out[R0 + cA] = contrib * (1.0f / 64.0f);
}

extern "C" void kernel_launch(void* const* d_in, const int* in_sizes, int n_in,
                              void* d_out, int out_size, void* d_ws, size_t ws_size,
                              hipStream_t stream) {
  (void)in_sizes; (void)n_in; (void)ws_size; (void)out_size;
  const float* obs     = (const float*)d_in[0];
  const float* actions = (const float*)d_in[1];
  const float* W1      = (const float*)d_in[2];
  const float* b1      = (const float*)d_in[3];
  const float* W2      = (const float*)d_in[4];
  const float* b2      = (const float*)d_in[5];
  const float* W3      = (const float*)d_in[6];
  const float* b3      = (const float*)d_in[7];

  float* pwbuf = (float*)d_ws;   // 131072 x 64 f32 = 33.5 MB

  TFKeys keys;
  for (unsigned j = 0; j < NCF; ++j) {
    unsigned o0, o1;
    tf2x32(0u, 42u, 0u, j, o0, o1);
    keys.k[2 * j]     = o0;
    keys.k[2 * j + 1] = o1;
  }

  hipLaunchKernelGGL(infl_fused, dim3(1024), dim3(512), 0, stream,
                     obs, actions, W1, b1, W2, b2, W3, b3, pwbuf,
                     (float*)d_out, keys);
}

// Round 12
// 560.986 us; speedup vs baseline: 1.7540x; 1.2055x over previous
//
#include <hip/hip_runtime.h>
#include <cstddef>

#define NCF 10

struct TFKeys { unsigned k[2 * NCF]; };

typedef __attribute__((ext_vector_type(8))) _Float16 f16x8;
typedef __attribute__((ext_vector_type(4))) float f32x4;

// Threefry-2x32, 20 rounds (JAX-compatible, partitionable semantics verified R1).
__host__ __device__ __forceinline__ void tf2x32(unsigned k0, unsigned k1,
                                                unsigned x0, unsigned x1,
                                                unsigned& o0, unsigned& o1) {
  const unsigned ks2 = k0 ^ k1 ^ 0x1BD11BDAu;
  x0 += k0; x1 += k1;
#define TF_R(r) x0 += x1; x1 = (x1 << (r)) | (x1 >> (32 - (r))); x1 ^= x0;
  TF_R(13) TF_R(15) TF_R(26) TF_R(6)
  x0 += k1;  x1 += ks2 + 1u;
  TF_R(17) TF_R(29) TF_R(16) TF_R(24)
  x0 += ks2; x1 += k0 + 2u;
  TF_R(13) TF_R(15) TF_R(26) TF_R(6)
  x0 += k0;  x1 += k1 + 3u;
  TF_R(17) TF_R(29) TF_R(16) TF_R(24)
  x0 += k1;  x1 += ks2 + 4u;
  TF_R(13) TF_R(15) TF_R(26) TF_R(6)
  x0 += ks2; x1 += k0 + 5u;
#undef TF_R
  o0 = x0; o1 = x1;
}

__device__ __forceinline__ float u01(unsigned bits) {
  return __uint_as_float((bits >> 9) | 0x3f800000u) - 1.0f;
}

// fp16x3 split of 8 floats: x = hi + lo, |x - hi - lo| <= 2^-24 |x|.
__device__ __forceinline__ void split44(const float4 a, const float4 b,
                                        f16x8& hh, f16x8& ll) {
  const float v[8] = {a.x, a.y, a.z, a.w, b.x, b.y, b.z, b.w};
#pragma unroll
  for (int e = 0; e < 8; ++e) {
    const _Float16 h = (_Float16)v[e];
    hh[e] = h;
    ll[e] = (_Float16)(v[e] - (float)h);
  }
}

// D += Ah*Bh + Ah*Bl + Al*Bh  (drops Al*Bl ~ 2^-24). A = activations, B = W.
#define MFMA3(acc, ah, al, bh, bl)                                          \
  acc = __builtin_amdgcn_mfma_f32_16x16x32_f16(ah, bh, acc, 0, 0, 0);       \
  acc = __builtin_amdgcn_mfma_f32_16x16x32_f16(ah, bl, acc, 0, 0, 0);       \
  acc = __builtin_amdgcn_mfma_f32_16x16x32_f16(al, bh, acc, 0, 0, 0);

// Stage W[K][N] (row-major f32) into hi/lo B-fragment layout (verified R2):
// frag elem ((kt*NTN+nt)*64+lane)*8+e <-> W[kt*32+(lane>>4)*8+e][nt*16+(lane&15)]
template <int K, int N>
__device__ __forceinline__ void stage_frags(const float* __restrict__ W,
                                            _Float16* fh, _Float16* fl, int t) {
  constexpr int NTN = N / 16;
  for (int i = t; i < K * N; i += 512) {
    const int e = i & 7, lane = (i >> 3) & 63, tile = i >> 9;
    const int kt = tile / NTN, nt = tile % NTN;
    const int k = kt * 32 + ((lane >> 4) << 3) + e;
    const int c = nt * 16 + (lane & 15);
    const float w = W[k * N + c];
    const _Float16 h = (_Float16)w;
    fh[i] = h;
    fl[i] = (_Float16)(w - (float)h);
  }
}

// [32][32] chunk buffer, XOR-swizzled (R4-verified pattern): writes/reads are
// <=2-way bank conflicts (free per m136).
__device__ __forceinline__ int swz(int row, int col) {
  return (row << 5) + (col ^ ((row & 7) << 2));
}

// ---------------------------------------------------------------------------
// Fused kernel, R3/R4 lineage, 32 SAMPLES PER WAVE (two 16-row A-tiles).
// Each weight-frag ds_read_b128 now feeds 2x the MFMA work -> per-sample LDS
// cost ~halved; 2x independent work per wave fills idle issue slots without
// needing block co-residency (proven unreachable R6-R10).
// __launch_bounds__(512, 1) = min-blocks 1 -> 2 waves/EU -> 256-VGPR cap
// (the toolchain model fitted to R2/R3/R4/R6/R8). pw parked in d_ws (R10
// trick) to keep peak regs ~220. LDS 112KB; no barriers / no global loads in
// the 12-pass loop. Numerics byte-identical to the verified R8 body per tile.
// (R11 bench was an infra failure — container acquisition; resubmitted as-is.)
// ---------------------------------------------------------------------------
__global__ __launch_bounds__(512, 1)
void infl_fused(const float* __restrict__ obs, const float* __restrict__ actions,
                const float* __restrict__ W1, const float* __restrict__ b1,
                const float* __restrict__ W2, const float* __restrict__ b2,
                const float* __restrict__ W3, const float* __restrict__ b3,
                float* __restrict__ pwbuf, float* __restrict__ out, TFKeys keys) {
  // Prologue: [0,65536) = W1-obs half frags. Pass loop: [0,81920) weight
  // frags; [81920,114688) = 8 x 4KB per-wave [32][32] chunk buffers.
  __shared__ __align__(16) unsigned char smem[114688];
  _Float16* w1oh = (_Float16*)smem;
  _Float16* w1ol = (_Float16*)(smem + 32768);
  _Float16* w1h  = (_Float16*)smem;
  _Float16* w1l  = (_Float16*)(smem + 16384);
  _Float16* w2h  = (_Float16*)(smem + 32768);
  _Float16* w2l  = (_Float16*)(smem + 49152);
  _Float16* w3h  = (_Float16*)(smem + 65536);
  _Float16* w3l  = (_Float16*)(smem + 73728);

  const int t = threadIdx.x, wave = t >> 6, lane = t & 63;
  const int R0 = blockIdx.x * 256 + wave * 32;   // wave owns 32 samples
  const int cA = lane & 15;            // A-row within tile (sample)
  const int kg = (lane >> 4) << 3;     // k base within 32-k tile
  const int r0 = (lane >> 4) << 2;     // C/D row base
  float* cb = (float*)(smem + 81920 + wave * 4096);

  // ========== prologue: ho[g] = b1 + obs @ W1[0:256] for both tiles =======
  f32x4 ho[2][8];
#pragma unroll
  for (int nt = 0; nt < 8; ++nt) {
    const float bv = b1[nt * 16 + cA];
    ho[0][nt] = (f32x4){bv, bv, bv, bv};
    ho[1][nt] = ho[0][nt];
  }
  {
    const float* orow0 = obs + (size_t)(R0 + cA) * 256;
    const float* orow1 = obs + (size_t)(R0 + 16 + cA) * 256;
    for (int half = 0; half < 2; ++half) {
      __syncthreads();   // previous half's MFMAs done reading frags
      stage_frags<128, 128>(W1 + half * 128 * 128, w1oh, w1ol, t);
      __syncthreads();
#pragma unroll
      for (int kt = 0; kt < 4; ++kt) {
        f16x8 oh0, ol0, oh1, ol1;
        {
          const float4 va = *(const float4*)(orow0 + half * 128 + kt * 32 + kg);
          const float4 vb = *(const float4*)(orow0 + half * 128 + kt * 32 + kg + 4);
          split44(va, vb, oh0, ol0);
          const float4 vc = *(const float4*)(orow1 + half * 128 + kt * 32 + kg);
          const float4 vd = *(const float4*)(orow1 + half * 128 + kt * 32 + kg + 4);
          split44(vc, vd, oh1, ol1);
        }
#pragma unroll
        for (int nt = 0; nt < 8; ++nt) {
          const int tile = kt * 8 + nt;
          const f16x8 bh = *(const f16x8*)&w1oh[(tile * 64 + lane) * 8];
          const f16x8 bl = *(const f16x8*)&w1ol[(tile * 64 + lane) * 8];
          MFMA3(ho[0][nt], oh0, ol0, bh, bl)
          MFMA3(ho[1][nt], oh1, ol1, bh, bl)
        }
      }
    }
  }
  __syncthreads();   // prologue reads done; restage pass weights

  stage_frags<64, 128>(W1 + 256 * 128, w1h, w1l, t);
  stage_frags<128, 64>(W2, w2h, w2l, t);
  stage_frags<64, 64>(W3, w3h, w3l, t);

  float b2r[4];
#pragma unroll
  for (int n2 = 0; n2 < 4; ++n2) b2r[n2] = b2[n2 * 16 + cA];
  __syncthreads();   // last barrier of the kernel

  // ============== MLP body (one pass), 2 sample-tiles per wave ============
#define MLP_BODY(HAS_ACT, acc3)                                              \
  {                                                                          \
    f32x4 a2[2][4];                                                          \
    _Pragma("unroll") for (int g = 0; g < 2; ++g)                            \
      _Pragma("unroll") for (int n2 = 0; n2 < 4; ++n2)                       \
        a2[g][n2] = (f32x4){b2r[n2], b2r[n2], b2r[n2], b2r[n2]};             \
    _Pragma("unroll") for (int c = 0; c < 4; ++c) {                          \
      f32x4 a10 = ho[0][2 * c], a11 = ho[0][2 * c + 1];                      \
      f32x4 a12 = ho[1][2 * c], a13 = ho[1][2 * c + 1];                      \
      if (HAS_ACT) {                                                         \
        _Pragma("unroll") for (int kt = 0; kt < 2; ++kt) {                   \
          const int t0 = ((kt * 8 + 2 * c) * 64 + lane) * 8;                 \
          const int t1 = ((kt * 8 + 2 * c + 1) * 64 + lane) * 8;             \
          const f16x8 bh0 = *(const f16x8*)&w1h[t0];                         \
          const f16x8 bl0 = *(const f16x8*)&w1l[t0];                         \
          MFMA3(a10, ah[0][kt], al[0][kt], bh0, bl0)                         \
          MFMA3(a12, ah[1][kt], al[1][kt], bh0, bl0)                         \
          const f16x8 bh1 = *(const f16x8*)&w1h[t1];                         \
          const f16x8 bl1 = *(const f16x8*)&w1l[t1];                         \
          MFMA3(a11, ah[0][kt], al[0][kt], bh1, bl1)                         \
          MFMA3(a13, ah[1][kt], al[1][kt], bh1, bl1)                         \
        }                                                                    \
      }                                                                      \
      _Pragma("unroll") for (int j = 0; j < 4; ++j) {                        \
        cb[swz(r0 + j, cA)]           = fmaxf(a10[j], 0.f);                  \
        cb[swz(r0 + j, 16 + cA)]      = fmaxf(a11[j], 0.f);                  \
        cb[swz(16 + r0 + j, cA)]      = fmaxf(a12[j], 0.f);                  \
        cb[swz(16 + r0 + j, 16 + cA)] = fmaxf(a13[j], 0.f);                  \
      }                                                                      \
      f16x8 hh0, hl0, hh1, hl1;                                              \
      {                                                                      \
        const float4 va = *(const float4*)&cb[swz(cA, kg)];                  \
        const float4 vb = *(const float4*)&cb[swz(cA, kg + 4)];              \
        split44(va, vb, hh0, hl0);                                           \
        const float4 vc = *(const float4*)&cb[swz(16 + cA, kg)];             \
        const float4 vd = *(const float4*)&cb[swz(16 + cA, kg + 4)];         \
        split44(vc, vd, hh1, hl1);                                           \
      }                                                                      \
      _Pragma("unroll") for (int n2 = 0; n2 < 4; ++n2) {                     \
        const int tt = ((c * 4 + n2) * 64 + lane) * 8;                       \
        const f16x8 wh = *(const f16x8*)&w2h[tt];                            \
        const f16x8 wl = *(const f16x8*)&w2l[tt];                            \
        MFMA3(a2[0][n2], hh0, hl0, wh, wl)                                   \
        MFMA3(a2[1][n2], hh1, hl1, wh, wl)                                   \
      }                                                                      \
    }                                                                        \
    _Pragma("unroll") for (int d = 0; d < 2; ++d) {                          \
      _Pragma("unroll") for (int j = 0; j < 4; ++j) {                        \
        cb[swz(r0 + j, cA)]           = fmaxf(a2[0][2 * d][j], 0.f);         \
        cb[swz(r0 + j, 16 + cA)]      = fmaxf(a2[0][2 * d + 1][j], 0.f);     \
        cb[swz(16 + r0 + j, cA)]      = fmaxf(a2[1][2 * d][j], 0.f);         \
        cb[swz(16 + r0 + j, 16 + cA)] = fmaxf(a2[1][2 * d + 1][j], 0.f);     \
      }                                                                      \
      f16x8 hh0, hl0, hh1, hl1;                                              \
      {                                                                      \
        const float4 va = *(const float4*)&cb[swz(cA, kg)];                  \
        const float4 vb = *(const float4*)&cb[swz(cA, kg + 4)];              \
        split44(va, vb, hh0, hl0);                                           \
        const float4 vc = *(const float4*)&cb[swz(16 + cA, kg)];             \
        const float4 vd = *(const float4*)&cb[swz(16 + cA, kg + 4)];         \
        split44(vc, vd, hh1, hl1);                                           \
      }                                                                      \
      _Pragma("unroll") for (int n3 = 0; n3 < 4; ++n3) {                     \
        const int tt = ((d * 4 + n3) * 64 + lane) * 8;                       \
        const f16x8 wh = *(const f16x8*)&w3h[tt];                            \
        const f16x8 wl = *(const f16x8*)&w3l[tt];                            \
        MFMA3(acc3[0][n3], hh0, hl0, wh, wl)                                 \
        MFMA3(acc3[1][n3], hh1, hl1, wh, wl)                                 \
      }                                                                      \
    }                                                                        \
  }

  // ---- with-actions pass FIRST -> pw -> parked in pwbuf (d_ws) ----
  {
    f16x8 ah[2][2], al[2][2];
#pragma unroll
    for (int g = 0; g < 2; ++g) {
      const float* arow = actions + (size_t)(R0 + g * 16 + cA) * 64 + kg;
#pragma unroll
      for (int kt = 0; kt < 2; ++kt) {
        const float4 va = *(const float4*)(arow + kt * 32);
        const float4 vb = *(const float4*)(arow + kt * 32 + 4);
        split44(va, vb, ah[g][kt], al[g][kt]);
      }
    }
    f32x4 pw[2][4];
#pragma unroll
    for (int g = 0; g < 2; ++g)
#pragma unroll
      for (int nt = 0; nt < 4; ++nt) pw[g][nt] = (f32x4){0.f, 0.f, 0.f, 0.f};
    MLP_BODY(true, pw)
#pragma unroll
    for (int g = 0; g < 2; ++g)
#pragma unroll
      for (int n3 = 0; n3 < 4; ++n3)
#pragma unroll
        for (int j = 0; j < 4; ++j)
          pwbuf[(size_t)(R0 + g * 16 + r0 + j) * 64 + n3 * 16 + cA] =
              pw[g][n3][j];
  }

  // ---- passes 0..10 -> pacc (p=0: zero actions, L1a skipped) ----
  f32x4 pacc[2][4];
#pragma unroll
  for (int g = 0; g < 2; ++g)
#pragma unroll
    for (int nt = 0; nt < 4; ++nt) pacc[g][nt] = (f32x4){0.f, 0.f, 0.f, 0.f};

  for (int p = 0; p < 11; ++p) {
    f16x8 ah[2][2], al[2][2];
    if (p >= 1) {
      const unsigned k0 = keys.k[2 * (p - 1)];
      const unsigned k1 = keys.k[2 * (p - 1) + 1];
#pragma unroll
      for (int g = 0; g < 2; ++g) {
        const unsigned base = (unsigned)(R0 + g * 16 + cA) * 64u + (unsigned)kg;
#pragma unroll
        for (int kt = 0; kt < 2; ++kt) {
          float v[8];
#pragma unroll
          for (int e = 0; e < 8; ++e) {
            unsigned o0, o1;
            tf2x32(k0, k1, 0u, base + (unsigned)(kt * 32 + e), o0, o1);
            v[e] = u01(o0 ^ o1);
          }
          split44(*(const float4*)&v[0], *(const float4*)&v[4],
                  ah[g][kt], al[g][kt]);
        }
      }
    }
    MLP_BODY(p != 0, pacc)
  }

  // ---- epilogue: reload pw; softmax/KL per row, 16-lane shfl reductions ----
  const float inv11 = 1.0f / 11.0f;
  float b3r[4];
#pragma unroll
  for (int n3 = 0; n3 < 4; ++n3) b3r[n3] = b3[n3 * 16 + cA];

#pragma unroll
  for (int g = 0; g < 2; ++g) {
#pragma unroll
    for (int j = 0; j < 4; ++j) {
      float pwv[4], pav[4];
#pragma unroll
      for (int nt = 0; nt < 4; ++nt) {
        pwv[nt] = pwbuf[(size_t)(R0 + g * 16 + r0 + j) * 64 + nt * 16 + cA] +
                  b3r[nt];
        pav[nt] = pacc[g][nt][j] * inv11 + b3r[nt];
      }
      float mw = fmaxf(fmaxf(pwv[0], pwv[1]), fmaxf(pwv[2], pwv[3]));
      float ma = fmaxf(fmaxf(pav[0], pav[1]), fmaxf(pav[2], pav[3]));
#pragma unroll
      for (int off = 1; off < 16; off <<= 1) {
        mw = fmaxf(mw, __shfl_xor(mw, off, 64));
        ma = fmaxf(ma, __shfl_xor(ma, off, 64));
      }
      float sw = 0.f, sa = 0.f;
#pragma unroll
      for (int nt = 0; nt < 4; ++nt) {
        sw += expf(pwv[nt] - mw);
        sa += expf(pav[nt] - ma);
      }
#pragma unroll
      for (int off = 1; off < 16; off <<= 1) {
        sw += __shfl_xor(sw, off, 64);
        sa += __shfl_xor(sa, off, 64);
      }
      const float lzw = logf(sw), lza = logf(sa);
      float contrib = 0.f;
#pragma unroll
      for (int nt = 0; nt < 4; ++nt) {
        const float lq = pav[nt] - ma - lza;
        const float lp = pwv[nt] - mw - lzw;
        contrib += expf(lq) * (lq - lp);
      }
#pragma unroll
      for (int off = 1; off < 16; off <<= 1)
        contrib += __shfl_xor(contrib, off, 64);
      if (cA == 0) out[R0 + g * 16 + r0 + j] = contrib * (1.0f / 64.0f);
    }
  }
}

extern "C" void kernel_launch(void* const* d_in, const int* in_sizes, int n_in,
                              void* d_out, int out_size, void* d_ws, size_t ws_size,
                              hipStream_t stream) {
  (void)in_sizes; (void)n_in; (void)ws_size; (void)out_size;
  const float* obs     = (const float*)d_in[0];
  const float* actions = (const float*)d_in[1];
  const float* W1      = (const float*)d_in[2];
  const float* b1      = (const float*)d_in[3];
  const float* W2      = (const float*)d_in[4];
  const float* b2      = (const float*)d_in[5];
  const float* W3      = (const float*)d_in[6];
  const float* b3      = (const float*)d_in[7];

  float* pwbuf = (float*)d_ws;   // 131072 x 64 f32 = 33.5 MB

  TFKeys keys;
  for (unsigned j = 0; j < NCF; ++j) {
    unsigned o0, o1;
    tf2x32(0u, 42u, 0u, j, o0, o1);
    keys.k[2 * j]     = o0;
    keys.k[2 * j + 1] = o1;
  }

  hipLaunchKernelGGL(infl_fused, dim3(512), dim3(512), 0, stream,
                     obs, actions, W1, b1, W2, b2, W3, b3, pwbuf,
                     (float*)d_out, keys);
}